// Round 1
// 605.308 us; speedup vs baseline: 1.2373x; 1.2373x over previous
//
#include <hip/hip_runtime.h>

// Problem constants (B,C,T,V)=(32,128,64,25), N_STEP=8, DILATION=1
#define CC     128
#define TT     64
#define VV     25
#define BB     32
#define PP     (TT * VV)          // 1600 positions per (b, c)
#define CHUNK  (BB * CC * PP)     // 6,553,600 elems per output chunk
#define NSTEP  8
#define PTILE  32                 // positions per block tile
#define NPT    (PP / PTILE)       // 50 tiles per batch

typedef __attribute__((ext_vector_type(8))) __bf16 bf16x8;   // MFMA A/B frag (4 VGPR)
typedef __attribute__((ext_vector_type(4))) float  f32x4;    // MFMA C/D frag

__device__ __forceinline__ float fast_tanh(float x) {
    // tanh(x) = 1 - 2/(exp(2x)+1); ~1e-7 abs err, threshold is 0.2.
    float e = __expf(2.0f * x);
    return 1.0f - 2.0f * __builtin_amdgcn_rcpf(e + 1.0f);
}

// Split fp32 into truncated-bf16 hi + truncated-bf16 lo (residual <= 2^-16 rel).
// y - hi is exact in fp32 (same exponent, low bits), so lo captures the next 8 bits.
__device__ __forceinline__ void bf16_split(float y, unsigned short& h, unsigned short& lo) {
    unsigned int bits = __float_as_uint(y);
    h = (unsigned short)(bits >> 16);
    float r = y - __uint_as_float(bits & 0xffff0000u);
    lo = (unsigned short)(__float_as_uint(r) >> 16);
}

// ---- tiny one-time kernel: W -> bf16 hi/lo pair in workspace ([d][c] row-major,
// c contiguous == MFMA A-frag k-contiguous layout; no transpose needed) ---------
__global__ void wsplit(const float* __restrict__ W,
                       unsigned short* __restrict__ Wh, unsigned short* __restrict__ Wl) {
    int idx = blockIdx.x * 256 + threadIdx.x;       // 16384 total
    if (idx < CC * CC) {
        unsigned short h, lo;
        bf16_split(W[idx], h, lo);
        Wh[idx] = h;
        Wl[idx] = lo;
    }
}

// ---- fused 8-step Euler kernel, split-bf16 MFMA channel mix -------------------
// Block owns (b, 32-position tile) x all 128 channels. fp32 state lives in
// REGISTERS (each lane keeps exactly its MFMA D-layout elements); LDS holds only
// the bf16 hi/lo copy of the state [p][c] (XOR-swizzled) for B-frag reads.
// Wave w computes d-tiles {2w,2w+1} x p-tiles {0,1}: 4 16x16 tiles, 48 MFMA/step.
__global__ __launch_bounds__(256) void euler_fused(
    const float* __restrict__ z, const unsigned short* __restrict__ Wh,
    const unsigned short* __restrict__ Wl, const float* __restrict__ bias,
    float* __restrict__ out)
{
    __shared__ float          Xs[CC][PTILE];    // 16 KB fp32 initial state (prologue only)
    __shared__ unsigned short Xbh[PTILE * CC];  // 8 KB bf16-hi state, [p][c], swizzled
    __shared__ unsigned short Xbl[PTILE * CC];  // 8 KB bf16-lo state

    const int b   = blockIdx.y;
    const int p0  = blockIdx.x * PTILE;
    const int tid = threadIdx.x;
    const int w   = tid >> 6;          // wave 0..3
    const int lr  = tid & 15;          // lane&15: A-row / B-col / D-col
    const int lh  = (tid >> 4) & 3;    // lane>>4: k-group / D-row-group

    // ---- A fragments: this wave's two 16-channel W tiles, hi+lo, in registers ----
    // A layout (16x16x32): row = lane&15, k = (lane>>4)*8 + 0..7 (contiguous).
    bf16x8 ah[2][4], al[2][4];
    #pragma unroll
    for (int dtl = 0; dtl < 2; ++dtl) {
        const int d = (2 * w + dtl) * 16 + lr;
        #pragma unroll
        for (int ks = 0; ks < 4; ++ks) {
            const int cb = ks * 32 + lh * 8;
            ah[dtl][ks] = *(const bf16x8*)(Wh + d * CC + cb);
            al[dtl][ks] = *(const bf16x8*)(Wl + d * CC + cb);
        }
    }

    // bias per accumulator row: d = (2w+dtl)*16 + lh*4 + j
    float bv[2][4];
    #pragma unroll
    for (int dtl = 0; dtl < 2; ++dtl)
        #pragma unroll
        for (int j = 0; j < 4; ++j)
            bv[dtl][j] = bias[(2 * w + dtl) * 16 + lh * 4 + j];

    // ---- prologue: load z tile, emit both chunk-0 outputs, build Xs + Xb ----
    const float* zb = z + (size_t)b * CC * PP + p0;
    #pragma unroll
    for (int it = 0; it < 4; ++it) {
        int slot = it * 256 + tid;                  // 1024 float4 slots
        int c  = slot >> 3;                         // 8 float4 per 32-pos row
        int po = (slot & 7) * 4;
        float4 v = *(const float4*)(zb + (size_t)c * PP + po);
        *(float4*)&Xs[c][po] = v;
        size_t o = (size_t)(b * CC + c) * PP + p0 + po;
        *(float4*)(out + o)                     = v;   // z_shift chunk 0 (= z)
        *(float4*)(out + (size_t)9 * CHUNK + o) = v;   // z_cls   chunk 0 (= z)
        float vv[4] = {v.x, v.y, v.z, v.w};
        #pragma unroll
        for (int e = 0; e < 4; ++e) {
            int p = po + e;
            unsigned short h, lo;
            bf16_split(vv[e], h, lo);
            int off = (p * 256 + c * 2) ^ ((p & 7) << 4);   // XOR-swizzled [p][c]
            *(unsigned short*)((char*)Xbh + off) = h;
            *(unsigned short*)((char*)Xbl + off) = lo;
        }
    }

    __syncthreads();

    // fp32 state registers: st[dtl][ntl][j] = X[d][p] at this lane's D-layout slots
    float st[2][2][4];
    #pragma unroll
    for (int dtl = 0; dtl < 2; ++dtl)
        #pragma unroll
        for (int ntl = 0; ntl < 2; ++ntl)
            #pragma unroll
            for (int j = 0; j < 4; ++j)
                st[dtl][ntl][j] = Xs[(2 * w + dtl) * 16 + lh * 4 + j][ntl * 16 + lr];

    const int swz = (lr & 7) << 4;

    for (int i = 1; i <= NSTEP; ++i) {
        f32x4 acc[2][2];
        #pragma unroll
        for (int a0 = 0; a0 < 2; ++a0)
            #pragma unroll
            for (int a1 = 0; a1 < 2; ++a1)
                acc[a0][a1] = (f32x4){0.0f, 0.0f, 0.0f, 0.0f};

        // ---- channel matmul: acc = Wh*xh + Wh*xl + Wl*xh (fp32 accum) ----
        // B layout (16x16x32): col = lane&15 (-> position), k contiguous per lane.
        #pragma unroll
        for (int ks = 0; ks < 4; ++ks) {
            const int ro0 = ((lr)      * 256 + ks * 64 + lh * 16) ^ swz;
            const int ro1 = ((16 + lr) * 256 + ks * 64 + lh * 16) ^ swz;
            bf16x8 bh0 = *(const bf16x8*)((const char*)Xbh + ro0);
            bf16x8 bh1 = *(const bf16x8*)((const char*)Xbh + ro1);
            bf16x8 bl0 = *(const bf16x8*)((const char*)Xbl + ro0);
            bf16x8 bl1 = *(const bf16x8*)((const char*)Xbl + ro1);
            #pragma unroll
            for (int dtl = 0; dtl < 2; ++dtl) {
                acc[dtl][0] = __builtin_amdgcn_mfma_f32_16x16x32_bf16(ah[dtl][ks], bh0, acc[dtl][0], 0, 0, 0);
                acc[dtl][1] = __builtin_amdgcn_mfma_f32_16x16x32_bf16(ah[dtl][ks], bh1, acc[dtl][1], 0, 0, 0);
                acc[dtl][0] = __builtin_amdgcn_mfma_f32_16x16x32_bf16(al[dtl][ks], bh0, acc[dtl][0], 0, 0, 0);
                acc[dtl][1] = __builtin_amdgcn_mfma_f32_16x16x32_bf16(al[dtl][ks], bh1, acc[dtl][1], 0, 0, 0);
                acc[dtl][0] = __builtin_amdgcn_mfma_f32_16x16x32_bf16(ah[dtl][ks], bl0, acc[dtl][0], 0, 0, 0);
                acc[dtl][1] = __builtin_amdgcn_mfma_f32_16x16x32_bf16(ah[dtl][ks], bl1, acc[dtl][1], 0, 0, 0);
            }
        }

        // ---- y = x_old + tanh(acc + bias); state stays in registers ----
        #pragma unroll
        for (int dtl = 0; dtl < 2; ++dtl)
            #pragma unroll
            for (int ntl = 0; ntl < 2; ++ntl)
                #pragma unroll
                for (int j = 0; j < 4; ++j)
                    st[dtl][ntl][j] += fast_tanh(acc[dtl][ntl][j] + bv[dtl][j]);

        __syncthreads();   // all B-frag reads of old Xb complete

        // ---- publish new bf16 hi/lo state to LDS (packed 4 channels / store) ----
        #pragma unroll
        for (int dtl = 0; dtl < 2; ++dtl) {
            const int dbase = (2 * w + dtl) * 16 + lh * 4;
            #pragma unroll
            for (int ntl = 0; ntl < 2; ++ntl) {
                const int p = ntl * 16 + lr;
                ushort4 hv, lv;
                bf16_split(st[dtl][ntl][0], hv.x, lv.x);
                bf16_split(st[dtl][ntl][1], hv.y, lv.y);
                bf16_split(st[dtl][ntl][2], hv.z, lv.z);
                bf16_split(st[dtl][ntl][3], hv.w, lv.w);
                const int off = (p * 256 + dbase * 2) ^ ((p & 7) << 4);
                *(ushort4*)((char*)Xbh + off) = hv;
                *(ushort4*)((char*)Xbl + off) = lv;
            }
        }

        __syncthreads();   // new Xb visible before next step's reads

        // ---- global stores for chunk i (overlap with next step's MFMA phase) ----
        const size_t shiftBase = (size_t)i * CHUNK;
        const size_t clsBase   = (size_t)(9 + i) * CHUNK;
        const int s = VV * i;   // flat-position shift (t -> t+i)
        #pragma unroll
        for (int dtl = 0; dtl < 2; ++dtl)
            #pragma unroll
            for (int ntl = 0; ntl < 2; ++ntl) {
                const int p = p0 + ntl * 16 + lr;
                #pragma unroll
                for (int j = 0; j < 4; ++j) {
                    const int d = (2 * w + dtl) * 16 + lh * 4 + j;
                    const size_t row = (size_t)(b * CC + d) * PP;
                    const float y = st[dtl][ntl][j];
                    out[clsBase + row + p] = y;                       // z_cls chunk i
                    const int q = p + s;
                    if (q < PP) out[shiftBase + row + q] = y;         // z_shift chunk i
                    if (p < s)  out[shiftBase + row + p] = 0.0f;      // leading zeros
                }
            }
    }
}

extern "C" void kernel_launch(void* const* d_in, const int* in_sizes, int n_in,
                              void* d_out, int out_size, void* d_ws, size_t ws_size,
                              hipStream_t stream) {
    const float* z    = (const float*)d_in[0];   // (32,128,64,25) fp32
    const float* W    = (const float*)d_in[1];   // (128,128) fp32
    const float* bias = (const float*)d_in[2];   // (128,) fp32
    float* out = (float*)d_out;                  // 18 * CHUNK fp32
    unsigned short* Wh = (unsigned short*)d_ws;  // 32 KB bf16-hi W
    unsigned short* Wl = Wh + CC * CC;           // 32 KB bf16-lo W

    hipLaunchKernelGGL(wsplit, dim3((CC * CC + 255) / 256), dim3(256), 0, stream, W, Wh, Wl);
    hipLaunchKernelGGL(euler_fused, dim3(NPT, BB), dim3(256), 0, stream, z, Wh, Wl, bias, out);
}